// Round 1
// 4839.090 us; speedup vs baseline: 2.5049x; 2.5049x over previous
//
#include <hip/hip_runtime.h>
#include <hip/hip_bf16.h>
#include <cstddef>

// ---------------------------------------------------------------------------
// MIGCL graph autoencoder forward.
//   z  = elu(bn(feat@eW0)); z = elu(bn(z@eW1))
//   per graph: s = z@gW1; h = relu(csr_gather(w*s[src]->dst) + gb1)
//              s2 = h@gW2; emb_g = csr_gather(w*s2[src]->dst) + gb2
//   attention softmax over 2 views -> emb
//   d = elu(bn(emb@dW0)); de = sigmoid(bn(d@dW1))
//
// R1 change vs baseline: atomic scatter (3.28 GB HBM write traffic per
// aggregation, 64x the useful 51 MB) replaced by dst-sorted CSR gather:
// hist -> scan -> permute (built per launch, ~13 MB scratch, ~50 us), then
// one wave per node accumulates its in-edges in registers and writes each
// output row exactly once, with bias+ReLU fused (kills the memset + bias
// dispatches as well).
//
// Scratch: z0/z1/s/agg + CSR live inside d_out's `de` region (written last).
//          decoder hidden `d` lives in d_ws (needs N*512*4 = 102.4 MB).
// ---------------------------------------------------------------------------

typedef __bf16 bf16x8 __attribute__((ext_vector_type(8)));
typedef float  f32x4  __attribute__((ext_vector_type(4)));

#define LDSP 40   // 32 k + 8 pad (bf16) -> 80B row stride, 16B aligned, 2-way bank alias only

__device__ __forceinline__ float elu_f(float x) {
    return x > 0.f ? x : (__expf(x) - 1.f);
}

// C = act(bn(A@B + bias)); A[M,K] fp32, B[K,N] fp32, C[M,N] fp32.
// ACT: 0 = none, 1 = BN+ELU, 2 = BN+sigmoid. bf16 MFMA 16x16x32, 64x64 tile.
template<int ACT, bool HAS_BIAS, bool HAS_BN>
__global__ __launch_bounds__(256)
void gemm_fused(const float* __restrict__ A, const float* __restrict__ B,
                const float* __restrict__ bias, const float* __restrict__ gamma,
                const float* __restrict__ beta, float* __restrict__ C,
                int M, int K, int N)
{
    __shared__ __align__(16) __bf16 As[64 * LDSP];   // [row][k]
    __shared__ __align__(16) __bf16 Bs[64 * LDSP];   // [n][k]  (transposed)

    const int t    = threadIdx.x;
    const int lane = t & 63;
    const int wv   = t >> 6;        // wave 0..3 -> rows wv*16..+16
    const int quad = lane >> 4;     // 0..3
    const int m16  = lane & 15;

    const int row0 = blockIdx.y * 64;
    const int col0 = blockIdx.x * 64;

    f32x4 acc[4];
#pragma unroll
    for (int i = 0; i < 4; ++i) acc[i] = (f32x4){0.f, 0.f, 0.f, 0.f};

    // staging maps
    const int ar = t >> 2;           // A row 0..63
    const int ak = (t & 3) << 3;     // A k 0,8,16,24
    const int bn = t & 63;           // B n 0..63
    const int bk = (t >> 6) << 3;    // B k 0,8,16,24
    const bool arow_ok = (row0 + ar) < M;
    const bool bcol_ok = (col0 + bn) < N;

    for (int k0 = 0; k0 < K; k0 += 32) {
        // ---- stage A tile (64x32), fp32 -> bf16 ----
        {
            const float* ap = A + (size_t)(row0 + ar) * K + (k0 + ak);
            bf16x8 v8;
            if (arow_ok && (k0 + ak + 8) <= K) {
                float4 u = *(const float4*)ap;
                float4 v = *(const float4*)(ap + 4);
                v8[0] = (__bf16)u.x; v8[1] = (__bf16)u.y;
                v8[2] = (__bf16)u.z; v8[3] = (__bf16)u.w;
                v8[4] = (__bf16)v.x; v8[5] = (__bf16)v.y;
                v8[6] = (__bf16)v.z; v8[7] = (__bf16)v.w;
            } else {
#pragma unroll
                for (int j = 0; j < 8; ++j) {
                    int kk = k0 + ak + j;
                    v8[j] = (arow_ok && kk < K) ? (__bf16)ap[j] : (__bf16)0.f;
                }
            }
            *(bf16x8*)&As[ar * LDSP + ak] = v8;
        }
        // ---- stage B tile transposed: Bs[n][k] <- B[k][n] ----
        {
            bf16x8 v8;
#pragma unroll
            for (int j = 0; j < 8; ++j) {
                int kk = k0 + bk + j;
                float v = (bcol_ok && kk < K) ? B[(size_t)kk * N + (col0 + bn)] : 0.f;
                v8[j] = (__bf16)v;
            }
            *(bf16x8*)&Bs[bn * LDSP + bk] = v8;
        }
        __syncthreads();

        // ---- MFMA: wave computes 16 rows x 64 cols ----
        bf16x8 a = *(const bf16x8*)&As[(wv * 16 + m16) * LDSP + quad * 8];
#pragma unroll
        for (int nt = 0; nt < 4; ++nt) {
            bf16x8 b = *(const bf16x8*)&Bs[(nt * 16 + m16) * LDSP + quad * 8];
            acc[nt] = __builtin_amdgcn_mfma_f32_16x16x32_bf16(a, b, acc[nt], 0, 0, 0);
        }
        __syncthreads();
    }

    // ---- epilogue: C/D layout col=lane&15, row=quad*4+reg (m89-verified) ----
    const float kBN = 0.99950037f;   // 1/sqrt(1 + 1e-3)
    const int orow = row0 + wv * 16 + quad * 4;
#pragma unroll
    for (int nt = 0; nt < 4; ++nt) {
        int gc = col0 + nt * 16 + m16;
        if (gc >= N) continue;
        float bi = HAS_BIAS ? bias[gc] : 0.f;
        float g  = HAS_BN ? gamma[gc] * kBN : 1.f;
        float bt = HAS_BN ? beta[gc] : 0.f;
#pragma unroll
        for (int r = 0; r < 4; ++r) {
            int gr = orow + r;
            if (gr >= M) continue;
            float x = acc[nt][r] + bi;
            if (HAS_BN) x = x * g + bt;
            if (ACT == 1) x = elu_f(x);
            else if (ACT == 2) x = 1.f / (1.f + __expf(-x));
            C[(size_t)gr * N + gc] = x;
        }
    }
}

// ---------------- CSR build: hist -> scan -> permute ----------------

// cnt[dst[e]]++ (cnt pre-zeroed via memset)
__global__ __launch_bounds__(256)
void hist_kernel(const int* __restrict__ dst, int* __restrict__ cnt, int E)
{
    int e = blockIdx.x * 256 + threadIdx.x;
    if (e >= E) return;
    atomicAdd(&cnt[dst[e]], 1);
}

// single-block exclusive scan over N counts; writes off[0..N] and resets
// cur[i] = off[i] (cnt and cur are the SAME array: read count, overwrite base).
__global__ __launch_bounds__(256)
void exscan_kernel(int* __restrict__ cntcur, int* __restrict__ off, int Nn)
{
    __shared__ int sums[256];
    const int t = threadIdx.x;
    const int chunk = (Nn + 255) / 256;
    const int lo = t * chunk;
    const int hi = min(lo + chunk, Nn);
    int s = 0;
    for (int i = lo; i < hi; ++i) s += cntcur[i];
    sums[t] = s;
    __syncthreads();
    if (t == 0) {
        int run = 0;
        for (int i = 0; i < 256; ++i) { int v = sums[i]; sums[i] = run; run += v; }
    }
    __syncthreads();
    int base = sums[t];
    for (int i = lo; i < hi; ++i) {
        int v = cntcur[i];          // read count first
        off[i] = base;
        cntcur[i] = base;           // becomes the permute cursor
        base += v;
    }
    if (t == 255) off[Nn] = base;   // == E (thread 255's chunk ends at Nn)
}

// sorted_{src,w}[pos] <- (src,w)[e] grouped by dst
__global__ __launch_bounds__(256)
void permute_kernel(const int* __restrict__ src, const int* __restrict__ dst,
                    const float* __restrict__ w, int* __restrict__ cur,
                    int* __restrict__ ssrc, float* __restrict__ sw, int E)
{
    int e = blockIdx.x * 256 + threadIdx.x;
    if (e >= E) return;
    int d = dst[e];
    int pos = atomicAdd(&cur[d], 1);
    ssrc[pos] = src[e];
    sw[pos]   = w[e];
}

// out[n] = act( sum_{j in seg(n)} w[j] * s[ssrc[j]] + bias ), one wave per node.
// VPL floats per lane (C = VPL*64). Coalesced 64-lane row reads; single write.
template<int VPL, int RELU>
__global__ __launch_bounds__(256)
void gather_agg_kernel(const float* __restrict__ s, const int* __restrict__ off,
                       const int* __restrict__ ssrc, const float* __restrict__ sw,
                       const float* __restrict__ bias, float* __restrict__ out, int Nn)
{
    const int node = blockIdx.x * 4 + (threadIdx.x >> 6);
    if (node >= Nn) return;
    const int lane = threadIdx.x & 63;
    const int C = VPL * 64;
    const int c = lane * VPL;

    const int beg = off[node], end = off[node + 1];
    float acc[VPL];
#pragma unroll
    for (int i = 0; i < VPL; ++i) acc[i] = 0.f;

    int j = beg;
    if (j < end) {
        int   sr = ssrc[j];
        float ww = sw[j];
        for (; j + 1 < end; ++j) {
            int   nsr = ssrc[j + 1];     // prefetch next edge descriptor
            float nww = sw[j + 1];
            const float* sp = s + (size_t)sr * C + c;
            if (VPL == 4) {
                float4 v = *(const float4*)sp;
                acc[0] += ww * v.x; acc[1] += ww * v.y;
                acc[2] += ww * v.z; acc[3] += ww * v.w;
            } else {
                float2 v = *(const float2*)sp;
                acc[0] += ww * v.x; acc[1] += ww * v.y;
            }
            sr = nsr; ww = nww;
        }
        const float* sp = s + (size_t)sr * C + c;
        if (VPL == 4) {
            float4 v = *(const float4*)sp;
            acc[0] += ww * v.x; acc[1] += ww * v.y;
            acc[2] += ww * v.z; acc[3] += ww * v.w;
        } else {
            float2 v = *(const float2*)sp;
            acc[0] += ww * v.x; acc[1] += ww * v.y;
        }
    }

    float* op = out + (size_t)node * C + c;
    if (VPL == 4) {
        float4 bv = *(const float4*)(bias + c);
        float4 o;
        o.x = acc[0] + bv.x; o.y = acc[1] + bv.y;
        o.z = acc[2] + bv.z; o.w = acc[3] + bv.w;
        if (RELU) {
            o.x = fmaxf(o.x, 0.f); o.y = fmaxf(o.y, 0.f);
            o.z = fmaxf(o.z, 0.f); o.w = fmaxf(o.w, 0.f);
        }
        *(float4*)op = o;
    } else {
        float2 bv = *(const float2*)(bias + c);
        float2 o;
        o.x = acc[0] + bv.x; o.y = acc[1] + bv.y;
        if (RELU) { o.x = fmaxf(o.x, 0.f); o.y = fmaxf(o.y, 0.f); }
        *(float2*)op = o;
    }
}

// attention over 2 views: beta = softmax([femb@aW, semb@aW]); emb = sum beta*view
// one wave per node, 2 dims per lane (EMB=128).
__global__ __launch_bounds__(256)
void attention_kernel(const float* __restrict__ femb, const float* __restrict__ semb,
                      const float* __restrict__ aW, float* __restrict__ emb, int Nn)
{
    int node = blockIdx.x * 4 + (threadIdx.x >> 6);
    int lane = threadIdx.x & 63;
    if (node >= Nn) return;
    const float2 f = *(const float2*)(femb + (size_t)node * 128 + lane * 2);
    const float2 s = *(const float2*)(semb + (size_t)node * 128 + lane * 2);
    const float2 a = *(const float2*)(aW + lane * 2);
    float pf = f.x * a.x + f.y * a.y;
    float ps = s.x * a.x + s.y * a.y;
#pragma unroll
    for (int off = 32; off; off >>= 1) {
        pf += __shfl_xor(pf, off);
        ps += __shfl_xor(ps, off);
    }
    float m = fmaxf(pf, ps);
    float ef = __expf(pf - m), es = __expf(ps - m);
    float inv = 1.f / (ef + es);
    float bf = ef * inv, bs = es * inv;
    float2 o;
    o.x = bf * f.x + bs * s.x;
    o.y = bf * f.y + bs * s.y;
    *(float2*)(emb + (size_t)node * 128 + lane * 2) = o;
}

extern "C" void kernel_launch(void* const* d_in, const int* in_sizes, int n_in,
                              void* d_out, int out_size, void* d_ws, size_t ws_size,
                              hipStream_t stream)
{
    const int NN = 50000, DIN = 3000, H0 = 512, H1 = 128, GH = 256, EMB = 128, D1 = 512;
    const int E = in_sizes[2];

    const float* feat = (const float*)d_in[0];
    const int*   fidx = (const int*)d_in[1];
    const float* fw   = (const float*)d_in[2];
    const int*   sidx = (const int*)d_in[3];
    const float* sw   = (const float*)d_in[4];
    const float* eW0  = (const float*)d_in[5];
    const float* eb0  = (const float*)d_in[6];
    const float* eg0  = (const float*)d_in[7];
    const float* ebt0 = (const float*)d_in[8];
    const float* eW1  = (const float*)d_in[9];
    const float* eb1  = (const float*)d_in[10];
    const float* eg1  = (const float*)d_in[11];
    const float* ebt1 = (const float*)d_in[12];
    const float* gW1  = (const float*)d_in[13];
    const float* gb1  = (const float*)d_in[14];
    const float* gW2  = (const float*)d_in[15];
    const float* gb2  = (const float*)d_in[16];
    const float* aW   = (const float*)d_in[17];
    const float* dW0  = (const float*)d_in[18];
    const float* db0  = (const float*)d_in[19];
    const float* dg0  = (const float*)d_in[20];
    const float* dbt0 = (const float*)d_in[21];
    const float* dW1  = (const float*)d_in[22];
    const float* db1  = (const float*)d_in[23];
    const float* dg1  = (const float*)d_in[24];
    const float* dbt1 = (const float*)d_in[25];

    float* out  = (float*)d_out;
    float* femb = out;
    float* semb = out + (size_t)NN * EMB;
    float* de   = out + (size_t)NN * EMB * 2;
    float* emb  = out + (size_t)NN * EMB * 2 + (size_t)NN * DIN;

    // scratch inside the (not-yet-written) de region: NN*3000 floats available
    float* z0 = de;                          // [NN,512]
    float* z1 = de + (size_t)NN * 512;       // [NN,128]
    float* sb = de + (size_t)NN * 640;       // [NN,256] (also reused as [NN,128])
    float* ag = de + (size_t)NN * 896;       // [NN,256]
    float* db = (float*)d_ws;                // [NN,512] decoder hidden (read while de written)

    // CSR scratch past the dense scratch: 2*(2N+1+2E)*4B ~= 13.6 MB << NN*1848*4B free
    int* csr = (int*)(de + (size_t)NN * 1152);
    int*   f_off = csr;                 // N+1
    int*   f_cur = f_off + (NN + 1);    // N   (counts, then cursors)
    int*   f_src = f_cur + NN;          // E   (dst-sorted src)
    float* f_w   = (float*)(f_src + E); // E   (dst-sorted w)
    int*   s_off = (int*)(f_w + E);     // N+1
    int*   s_cur = s_off + (NN + 1);    // N
    int*   s_src = s_cur + NN;          // E
    float* s_w   = (float*)(s_src + E); // E

    dim3 blk(256);
    auto cdiv = [](int a, int b) { return (a + b - 1) / b; };
    const int eb = cdiv(E, 256);

    // ---- build dst-sorted CSR for both graphs ----
    hipMemsetAsync(f_cur, 0, (size_t)NN * sizeof(int), stream);
    hipMemsetAsync(s_cur, 0, (size_t)NN * sizeof(int), stream);
    hist_kernel<<<eb, blk, 0, stream>>>(fidx + E, f_cur, E);
    hist_kernel<<<eb, blk, 0, stream>>>(sidx + E, s_cur, E);
    exscan_kernel<<<1, blk, 0, stream>>>(f_cur, f_off, NN);
    exscan_kernel<<<1, blk, 0, stream>>>(s_cur, s_off, NN);
    permute_kernel<<<eb, blk, 0, stream>>>(fidx, fidx + E, fw, f_cur, f_src, f_w, E);
    permute_kernel<<<eb, blk, 0, stream>>>(sidx, sidx + E, sw, s_cur, s_src, s_w, E);

    // ---- encoder ----
    gemm_fused<1, true, true><<<dim3(cdiv(H0, 64), cdiv(NN, 64)), blk, 0, stream>>>(
        feat, eW0, eb0, eg0, ebt0, z0, NN, DIN, H0);
    gemm_fused<1, true, true><<<dim3(cdiv(H1, 64), cdiv(NN, 64)), blk, 0, stream>>>(
        z0, eW1, eb1, eg1, ebt1, z1, NN, H0, H1);

    // ---- two GCN branches (shared weights), CSR gather instead of scatter ----
    for (int g = 0; g < 2; ++g) {
        const int*   off    = g ? s_off : f_off;
        const int*   esrc   = g ? s_src : f_src;
        const float* ew     = g ? s_w : f_w;
        float*       embout = g ? semb : femb;

        gemm_fused<0, false, false><<<dim3(cdiv(GH, 64), cdiv(NN, 64)), blk, 0, stream>>>(
            z1, gW1, nullptr, nullptr, nullptr, sb, NN, H1, GH);
        gather_agg_kernel<4, 1><<<cdiv(NN, 4), blk, 0, stream>>>(
            sb, off, esrc, ew, gb1, ag, NN);

        gemm_fused<0, false, false><<<dim3(cdiv(EMB, 64), cdiv(NN, 64)), blk, 0, stream>>>(
            ag, gW2, nullptr, nullptr, nullptr, sb, NN, GH, EMB);
        gather_agg_kernel<2, 0><<<cdiv(NN, 4), blk, 0, stream>>>(
            sb, off, esrc, ew, gb2, embout, NN);
    }

    // ---- attention pooling -> emb ----
    attention_kernel<<<cdiv(NN, 4), blk, 0, stream>>>(femb, semb, aW, emb, NN);

    // ---- decoder ----
    gemm_fused<1, true, true><<<dim3(cdiv(D1, 64), cdiv(NN, 64)), blk, 0, stream>>>(
        emb, dW0, db0, dg0, dbt0, db, NN, EMB, D1);
    gemm_fused<2, true, true><<<dim3(cdiv(DIN, 64), cdiv(NN, 64)), blk, 0, stream>>>(
        db, dW1, db1, dg1, dbt1, de, NN, D1, DIN);
}

// Round 2
// 3317.658 us; speedup vs baseline: 3.6537x; 1.4586x over previous
//
#include <hip/hip_runtime.h>
#include <hip/hip_bf16.h>
#include <cstddef>

// ---------------------------------------------------------------------------
// MIGCL graph autoencoder forward.
//   z  = elu(bn(feat@eW0)); z = elu(bn(z@eW1))
//   per graph: s = z@gW1; h = relu(csr_gather(w*s[src]->dst) + gb1)
//              s2 = h@gW2; emb_g = csr_gather(w*s2[src]->dst) + gb2
//   attention softmax over 2 views -> emb
//   d = elu(bn(emb@dW0)); de = sigmoid(bn(d@dW1))
//
// R2 change: GEMM rebuilt as 128x128 tile (m93 ladder structure).
//   - 4 waves in 2x2 grid, each owns 64x64 = 4x4 fragments of 16x16x32 bf16
//     MFMA -> 16 MFMAs per wave per K-step; intensity 64 FLOP/byte (was 16).
//   - staging maps row=t>>1, k-half=(t&1)*16: each lane writes one 16B
//     granule; 80B row stride -> 2-way bank alias only (free), killing the
//     8-way ds_write conflict of the old n=t&63 map (6.6e7 conflicts/disp).
//   - fp32->bf16 conversion stays in registers (numerics unchanged).
//
// Scratch: z0/z1/s/agg + CSR live inside d_out's `de` region (written last).
//          decoder hidden `d` lives in d_ws (needs N*512*4 = 102.4 MB).
// ---------------------------------------------------------------------------

typedef __bf16 bf16x8 __attribute__((ext_vector_type(8)));
typedef float  f32x4  __attribute__((ext_vector_type(4)));

#define LDSP 40   // 32 k + 8 pad (bf16) -> 80B row stride, 16B aligned

__device__ __forceinline__ float elu_f(float x) {
    return x > 0.f ? x : (__expf(x) - 1.f);
}

// C = act(bn(A@B + bias)); A[M,K] fp32, B[K,N] fp32, C[M,N] fp32.
// ACT: 0 = none, 1 = BN+ELU, 2 = BN+sigmoid. bf16 MFMA 16x16x32, 128x128 tile.
template<int ACT, bool HAS_BIAS, bool HAS_BN>
__global__ __launch_bounds__(256)
void gemm_fused(const float* __restrict__ A, const float* __restrict__ B,
                const float* __restrict__ bias, const float* __restrict__ gamma,
                const float* __restrict__ beta, float* __restrict__ C,
                int M, int K, int N)
{
    __shared__ __align__(16) __bf16 As[128 * LDSP];   // [row][k]
    __shared__ __align__(16) __bf16 Bs[128 * LDSP];   // [n][k]  (transposed)

    const int t    = threadIdx.x;
    const int lane = t & 63;
    const int wv   = t >> 6;        // wave 0..3 -> 2x2 grid of 64x64 blocks
    const int quad = lane >> 4;     // 0..3
    const int m16  = lane & 15;
    const int wr   = (wv >> 1) * 64;   // wave row offset within tile
    const int wc   = (wv & 1) * 64;    // wave col offset within tile

    const int row0 = blockIdx.y * 128;
    const int col0 = blockIdx.x * 128;

    f32x4 acc[4][4];
#pragma unroll
    for (int i = 0; i < 4; ++i)
#pragma unroll
        for (int j = 0; j < 4; ++j) acc[i][j] = (f32x4){0.f, 0.f, 0.f, 0.f};

    // staging maps: each thread stages one 16-element (32B fp32 -> 16B bf16)
    // granule of A and of B. row = t>>1 (0..127), k-half = (t&1)*16.
    const int sr  = t >> 1;
    const int sk  = (t & 1) << 4;
    const bool arow_ok = (row0 + sr) < M;
    const bool bcol_ok = (col0 + sr) < N;

    for (int k0 = 0; k0 < K; k0 += 32) {
        // ---- stage A granule: A[row0+sr][k0+sk .. +16] -> bf16 ----
        {
            const float* ap = A + (size_t)(row0 + sr) * K + (k0 + sk);
            bf16x8 v0, v1;
            if (arow_ok && (k0 + sk + 16) <= K) {
                float4 u0 = *(const float4*)ap;
                float4 u1 = *(const float4*)(ap + 4);
                float4 u2 = *(const float4*)(ap + 8);
                float4 u3 = *(const float4*)(ap + 12);
                v0[0] = (__bf16)u0.x; v0[1] = (__bf16)u0.y;
                v0[2] = (__bf16)u0.z; v0[3] = (__bf16)u0.w;
                v0[4] = (__bf16)u1.x; v0[5] = (__bf16)u1.y;
                v0[6] = (__bf16)u1.z; v0[7] = (__bf16)u1.w;
                v1[0] = (__bf16)u2.x; v1[1] = (__bf16)u2.y;
                v1[2] = (__bf16)u2.z; v1[3] = (__bf16)u2.w;
                v1[4] = (__bf16)u3.x; v1[5] = (__bf16)u3.y;
                v1[6] = (__bf16)u3.z; v1[7] = (__bf16)u3.w;
            } else {
#pragma unroll
                for (int j = 0; j < 8; ++j) {
                    int kk = k0 + sk + j;
                    v0[j] = (arow_ok && kk < K) ? (__bf16)ap[j] : (__bf16)0.f;
                }
#pragma unroll
                for (int j = 0; j < 8; ++j) {
                    int kk = k0 + sk + 8 + j;
                    v1[j] = (arow_ok && kk < K) ? (__bf16)ap[8 + j] : (__bf16)0.f;
                }
            }
            *(bf16x8*)&As[sr * LDSP + sk]     = v0;
            *(bf16x8*)&As[sr * LDSP + sk + 8] = v1;
        }
        // ---- stage B granule transposed: Bs[n][k] <- B[k][n] ----
        {
            const float* bp = B + (size_t)(k0 + sk) * N + (col0 + sr);
            bf16x8 w0, w1;
            if (bcol_ok && (k0 + sk + 16) <= K) {
#pragma unroll
                for (int j = 0; j < 8; ++j) w0[j] = (__bf16)bp[(size_t)j * N];
#pragma unroll
                for (int j = 0; j < 8; ++j) w1[j] = (__bf16)bp[(size_t)(8 + j) * N];
            } else {
#pragma unroll
                for (int j = 0; j < 8; ++j) {
                    int kk = k0 + sk + j;
                    w0[j] = (bcol_ok && kk < K) ? (__bf16)bp[(size_t)j * N] : (__bf16)0.f;
                }
#pragma unroll
                for (int j = 0; j < 8; ++j) {
                    int kk = k0 + sk + 8 + j;
                    w1[j] = (bcol_ok && kk < K) ? (__bf16)bp[(size_t)(8 + j) * N] : (__bf16)0.f;
                }
            }
            *(bf16x8*)&Bs[sr * LDSP + sk]     = w0;
            *(bf16x8*)&Bs[sr * LDSP + sk + 8] = w1;
        }
        __syncthreads();

        // ---- MFMA: wave computes 64x64 via 4x4 fragments ----
        bf16x8 af[4], bf[4];
#pragma unroll
        for (int mi = 0; mi < 4; ++mi)
            af[mi] = *(const bf16x8*)&As[(wr + mi * 16 + m16) * LDSP + quad * 8];
#pragma unroll
        for (int ni = 0; ni < 4; ++ni)
            bf[ni] = *(const bf16x8*)&Bs[(wc + ni * 16 + m16) * LDSP + quad * 8];
#pragma unroll
        for (int mi = 0; mi < 4; ++mi)
#pragma unroll
            for (int ni = 0; ni < 4; ++ni)
                acc[mi][ni] = __builtin_amdgcn_mfma_f32_16x16x32_bf16(
                    af[mi], bf[ni], acc[mi][ni], 0, 0, 0);
        __syncthreads();
    }

    // ---- epilogue: C/D layout col=lane&15, row=quad*4+reg (m89-verified) ----
    const float kBN = 0.99950037f;   // 1/sqrt(1 + 1e-3)
#pragma unroll
    for (int ni = 0; ni < 4; ++ni) {
        int gc = col0 + wc + ni * 16 + m16;
        if (gc >= N) continue;
        float bi = HAS_BIAS ? bias[gc] : 0.f;
        float g  = HAS_BN ? gamma[gc] * kBN : 1.f;
        float bt = HAS_BN ? beta[gc] : 0.f;
#pragma unroll
        for (int mi = 0; mi < 4; ++mi) {
            int orow = row0 + wr + mi * 16 + quad * 4;
#pragma unroll
            for (int r = 0; r < 4; ++r) {
                int gr = orow + r;
                if (gr >= M) continue;
                float x = acc[mi][ni][r] + bi;
                if (HAS_BN) x = x * g + bt;
                if (ACT == 1) x = elu_f(x);
                else if (ACT == 2) x = 1.f / (1.f + __expf(-x));
                C[(size_t)gr * N + gc] = x;
            }
        }
    }
}

// ---------------- CSR build: hist -> scan -> permute ----------------

// cnt[dst[e]]++ (cnt pre-zeroed via memset)
__global__ __launch_bounds__(256)
void hist_kernel(const int* __restrict__ dst, int* __restrict__ cnt, int E)
{
    int e = blockIdx.x * 256 + threadIdx.x;
    if (e >= E) return;
    atomicAdd(&cnt[dst[e]], 1);
}

// single-block exclusive scan over N counts; writes off[0..N] and resets
// cur[i] = off[i] (cnt and cur are the SAME array: read count, overwrite base).
__global__ __launch_bounds__(256)
void exscan_kernel(int* __restrict__ cntcur, int* __restrict__ off, int Nn)
{
    __shared__ int sums[256];
    const int t = threadIdx.x;
    const int chunk = (Nn + 255) / 256;
    const int lo = t * chunk;
    const int hi = min(lo + chunk, Nn);
    int s = 0;
    for (int i = lo; i < hi; ++i) s += cntcur[i];
    sums[t] = s;
    __syncthreads();
    if (t == 0) {
        int run = 0;
        for (int i = 0; i < 256; ++i) { int v = sums[i]; sums[i] = run; run += v; }
    }
    __syncthreads();
    int base = sums[t];
    for (int i = lo; i < hi; ++i) {
        int v = cntcur[i];          // read count first
        off[i] = base;
        cntcur[i] = base;           // becomes the permute cursor
        base += v;
    }
    if (t == 255) off[Nn] = base;   // == E (thread 255's chunk ends at Nn)
}

// sorted_{src,w}[pos] <- (src,w)[e] grouped by dst
__global__ __launch_bounds__(256)
void permute_kernel(const int* __restrict__ src, const int* __restrict__ dst,
                    const float* __restrict__ w, int* __restrict__ cur,
                    int* __restrict__ ssrc, float* __restrict__ sw, int E)
{
    int e = blockIdx.x * 256 + threadIdx.x;
    if (e >= E) return;
    int d = dst[e];
    int pos = atomicAdd(&cur[d], 1);
    ssrc[pos] = src[e];
    sw[pos]   = w[e];
}

// out[n] = act( sum_{j in seg(n)} w[j] * s[ssrc[j]] + bias ), one wave per node.
// VPL floats per lane (C = VPL*64). Coalesced 64-lane row reads; single write.
template<int VPL, int RELU>
__global__ __launch_bounds__(256)
void gather_agg_kernel(const float* __restrict__ s, const int* __restrict__ off,
                       const int* __restrict__ ssrc, const float* __restrict__ sw,
                       const float* __restrict__ bias, float* __restrict__ out, int Nn)
{
    const int node = blockIdx.x * 4 + (threadIdx.x >> 6);
    if (node >= Nn) return;
    const int lane = threadIdx.x & 63;
    const int C = VPL * 64;
    const int c = lane * VPL;

    const int beg = off[node], end = off[node + 1];
    float acc[VPL];
#pragma unroll
    for (int i = 0; i < VPL; ++i) acc[i] = 0.f;

    int j = beg;
    if (j < end) {
        int   sr = ssrc[j];
        float ww = sw[j];
        for (; j + 1 < end; ++j) {
            int   nsr = ssrc[j + 1];     // prefetch next edge descriptor
            float nww = sw[j + 1];
            const float* sp = s + (size_t)sr * C + c;
            if (VPL == 4) {
                float4 v = *(const float4*)sp;
                acc[0] += ww * v.x; acc[1] += ww * v.y;
                acc[2] += ww * v.z; acc[3] += ww * v.w;
            } else {
                float2 v = *(const float2*)sp;
                acc[0] += ww * v.x; acc[1] += ww * v.y;
            }
            sr = nsr; ww = nww;
        }
        const float* sp = s + (size_t)sr * C + c;
        if (VPL == 4) {
            float4 v = *(const float4*)sp;
            acc[0] += ww * v.x; acc[1] += ww * v.y;
            acc[2] += ww * v.z; acc[3] += ww * v.w;
        } else {
            float2 v = *(const float2*)sp;
            acc[0] += ww * v.x; acc[1] += ww * v.y;
        }
    }

    float* op = out + (size_t)node * C + c;
    if (VPL == 4) {
        float4 bv = *(const float4*)(bias + c);
        float4 o;
        o.x = acc[0] + bv.x; o.y = acc[1] + bv.y;
        o.z = acc[2] + bv.z; o.w = acc[3] + bv.w;
        if (RELU) {
            o.x = fmaxf(o.x, 0.f); o.y = fmaxf(o.y, 0.f);
            o.z = fmaxf(o.z, 0.f); o.w = fmaxf(o.w, 0.f);
        }
        *(float4*)op = o;
    } else {
        float2 bv = *(const float2*)(bias + c);
        float2 o;
        o.x = acc[0] + bv.x; o.y = acc[1] + bv.y;
        if (RELU) { o.x = fmaxf(o.x, 0.f); o.y = fmaxf(o.y, 0.f); }
        *(float2*)op = o;
    }
}

// attention over 2 views: beta = softmax([femb@aW, semb@aW]); emb = sum beta*view
// one wave per node, 2 dims per lane (EMB=128).
__global__ __launch_bounds__(256)
void attention_kernel(const float* __restrict__ femb, const float* __restrict__ semb,
                      const float* __restrict__ aW, float* __restrict__ emb, int Nn)
{
    int node = blockIdx.x * 4 + (threadIdx.x >> 6);
    int lane = threadIdx.x & 63;
    if (node >= Nn) return;
    const float2 f = *(const float2*)(femb + (size_t)node * 128 + lane * 2);
    const float2 s = *(const float2*)(semb + (size_t)node * 128 + lane * 2);
    const float2 a = *(const float2*)(aW + lane * 2);
    float pf = f.x * a.x + f.y * a.y;
    float ps = s.x * a.x + s.y * a.y;
#pragma unroll
    for (int off = 32; off; off >>= 1) {
        pf += __shfl_xor(pf, off);
        ps += __shfl_xor(ps, off);
    }
    float m = fmaxf(pf, ps);
    float ef = __expf(pf - m), es = __expf(ps - m);
    float inv = 1.f / (ef + es);
    float bf = ef * inv, bs = es * inv;
    float2 o;
    o.x = bf * f.x + bs * s.x;
    o.y = bf * f.y + bs * s.y;
    *(float2*)(emb + (size_t)node * 128 + lane * 2) = o;
}

extern "C" void kernel_launch(void* const* d_in, const int* in_sizes, int n_in,
                              void* d_out, int out_size, void* d_ws, size_t ws_size,
                              hipStream_t stream)
{
    const int NN = 50000, DIN = 3000, H0 = 512, H1 = 128, GH = 256, EMB = 128, D1 = 512;
    const int E = in_sizes[2];

    const float* feat = (const float*)d_in[0];
    const int*   fidx = (const int*)d_in[1];
    const float* fw   = (const float*)d_in[2];
    const int*   sidx = (const int*)d_in[3];
    const float* sw   = (const float*)d_in[4];
    const float* eW0  = (const float*)d_in[5];
    const float* eb0  = (const float*)d_in[6];
    const float* eg0  = (const float*)d_in[7];
    const float* ebt0 = (const float*)d_in[8];
    const float* eW1  = (const float*)d_in[9];
    const float* eb1  = (const float*)d_in[10];
    const float* eg1  = (const float*)d_in[11];
    const float* ebt1 = (const float*)d_in[12];
    const float* gW1  = (const float*)d_in[13];
    const float* gb1  = (const float*)d_in[14];
    const float* gW2  = (const float*)d_in[15];
    const float* gb2  = (const float*)d_in[16];
    const float* aW   = (const float*)d_in[17];
    const float* dW0  = (const float*)d_in[18];
    const float* db0  = (const float*)d_in[19];
    const float* dg0  = (const float*)d_in[20];
    const float* dbt0 = (const float*)d_in[21];
    const float* dW1  = (const float*)d_in[22];
    const float* db1  = (const float*)d_in[23];
    const float* dg1  = (const float*)d_in[24];
    const float* dbt1 = (const float*)d_in[25];

    float* out  = (float*)d_out;
    float* femb = out;
    float* semb = out + (size_t)NN * EMB;
    float* de   = out + (size_t)NN * EMB * 2;
    float* emb  = out + (size_t)NN * EMB * 2 + (size_t)NN * DIN;

    // scratch inside the (not-yet-written) de region: NN*3000 floats available
    float* z0 = de;                          // [NN,512]
    float* z1 = de + (size_t)NN * 512;       // [NN,128]
    float* sb = de + (size_t)NN * 640;       // [NN,256] (also reused as [NN,128])
    float* ag = de + (size_t)NN * 896;       // [NN,256]
    float* db = (float*)d_ws;                // [NN,512] decoder hidden (read while de written)

    // CSR scratch past the dense scratch: 2*(2N+1+2E)*4B ~= 13.6 MB << NN*1848*4B free
    int* csr = (int*)(de + (size_t)NN * 1152);
    int*   f_off = csr;                 // N+1
    int*   f_cur = f_off + (NN + 1);    // N   (counts, then cursors)
    int*   f_src = f_cur + NN;          // E   (dst-sorted src)
    float* f_w   = (float*)(f_src + E); // E   (dst-sorted w)
    int*   s_off = (int*)(f_w + E);     // N+1
    int*   s_cur = s_off + (NN + 1);    // N
    int*   s_src = s_cur + NN;          // E
    float* s_w   = (float*)(s_src + E); // E

    dim3 blk(256);
    auto cdiv = [](int a, int b) { return (a + b - 1) / b; };
    const int eb = cdiv(E, 256);

    // ---- build dst-sorted CSR for both graphs ----
    hipMemsetAsync(f_cur, 0, (size_t)NN * sizeof(int), stream);
    hipMemsetAsync(s_cur, 0, (size_t)NN * sizeof(int), stream);
    hist_kernel<<<eb, blk, 0, stream>>>(fidx + E, f_cur, E);
    hist_kernel<<<eb, blk, 0, stream>>>(sidx + E, s_cur, E);
    exscan_kernel<<<1, blk, 0, stream>>>(f_cur, f_off, NN);
    exscan_kernel<<<1, blk, 0, stream>>>(s_cur, s_off, NN);
    permute_kernel<<<eb, blk, 0, stream>>>(fidx, fidx + E, fw, f_cur, f_src, f_w, E);
    permute_kernel<<<eb, blk, 0, stream>>>(sidx, sidx + E, sw, s_cur, s_src, s_w, E);

    // ---- encoder ----
    gemm_fused<1, true, true><<<dim3(cdiv(H0, 128), cdiv(NN, 128)), blk, 0, stream>>>(
        feat, eW0, eb0, eg0, ebt0, z0, NN, DIN, H0);
    gemm_fused<1, true, true><<<dim3(cdiv(H1, 128), cdiv(NN, 128)), blk, 0, stream>>>(
        z0, eW1, eb1, eg1, ebt1, z1, NN, H0, H1);

    // ---- two GCN branches (shared weights), CSR gather instead of scatter ----
    for (int g = 0; g < 2; ++g) {
        const int*   off    = g ? s_off : f_off;
        const int*   esrc   = g ? s_src : f_src;
        const float* ew     = g ? s_w : f_w;
        float*       embout = g ? semb : femb;

        gemm_fused<0, false, false><<<dim3(cdiv(GH, 128), cdiv(NN, 128)), blk, 0, stream>>>(
            z1, gW1, nullptr, nullptr, nullptr, sb, NN, H1, GH);
        gather_agg_kernel<4, 1><<<cdiv(NN, 4), blk, 0, stream>>>(
            sb, off, esrc, ew, gb1, ag, NN);

        gemm_fused<0, false, false><<<dim3(cdiv(EMB, 128), cdiv(NN, 128)), blk, 0, stream>>>(
            ag, gW2, nullptr, nullptr, nullptr, sb, NN, GH, EMB);
        gather_agg_kernel<2, 0><<<cdiv(NN, 4), blk, 0, stream>>>(
            sb, off, esrc, ew, gb2, embout, NN);
    }

    // ---- attention pooling -> emb ----
    attention_kernel<<<cdiv(NN, 4), blk, 0, stream>>>(femb, semb, aW, emb, NN);

    // ---- decoder ----
    gemm_fused<1, true, true><<<dim3(cdiv(D1, 128), cdiv(NN, 128)), blk, 0, stream>>>(
        emb, dW0, db0, dg0, dbt0, db, NN, EMB, D1);
    gemm_fused<2, true, true><<<dim3(cdiv(DIN, 128), cdiv(NN, 128)), blk, 0, stream>>>(
        db, dW1, db1, dg1, dbt1, de, NN, D1, DIN);
}